// Round 1
// baseline (1540.689 us; speedup 1.0000x reference)
//
#include <hip/hip_runtime.h>
#include <stdint.h>

#define NR 8192
#define DD 512
#define KB 64
#define NT_K (NR / KB)   // 128
#define SCALE_H 8.0f
#define ITAU 30.0f
#define PSTR 144                 // P row stride (bytes), 16B-aligned
#define PBASE (KB * DD * 2)      // 65536 bytes of K tile
#define YSTRB 1040               // infoloob Y row stride bytes (512*2 + 16 pad)

typedef __bf16 bf16x8 __attribute__((ext_vector_type(8)));
typedef float f32x4 __attribute__((ext_vector_type(4)));
typedef unsigned int u32x2 __attribute__((ext_vector_type(2)));

__device__ __forceinline__ bf16x8 as_bf16x8(uint4 u) {
  union { uint4 a; bf16x8 b; } x; x.a = u; return x.b;
}
__device__ __forceinline__ unsigned short f2bf(float f) {
  unsigned u = __float_as_uint(f);
  u += 0x7FFFu + ((u >> 16) & 1u);
  return (unsigned short)(u >> 16);
}
__device__ __forceinline__ bf16x8 pack_tr(u32x2 a, u32x2 b) {
  uint4 w; w.x = a[0]; w.y = a[1]; w.z = b[0]; w.w = b[1];
  return as_bf16x8(w);
}

// ---------------- fp32 -> bf16 conversion ----------------
__global__ void cvt_kernel(const float* __restrict__ a, const float* __restrict__ b,
                           unsigned short* __restrict__ oa, unsigned short* __restrict__ ob) {
  const int n4 = NR * DD / 4;
  int t = blockIdx.x * blockDim.x + threadIdx.x;
  const float4* s; unsigned short* d; int i;
  if (t < n4) { s = (const float4*)a; d = oa; i = t; }
  else        { s = (const float4*)b; d = ob; i = t - n4; }
  float4 v = s[i];
  ushort4 o;
  o.x = f2bf(v.x); o.y = f2bf(v.y); o.z = f2bf(v.z); o.w = f2bf(v.w);
  *(ushort4*)(d + 4 * (size_t)i) = o;
}

__global__ void init_kernel(float* a) { if (threadIdx.x < 4) a[threadIdx.x] = 0.f; }

// ---------------- hopfield: flash attention + row normalize ----------------
// combo 0: Q=img K=img (p_xx) | 1: Q=txt K=txt (p_yy) | 2: Q=txt K=img (p_xy) | 3: Q=img K=txt (p_yx)
// K tile LDS layout: subtiles [s=kv/4][t=d/16][4][16] (128B each) so that
//   - QK^T B-frag = ds_read_b128 (feat-contiguous within a subtile row)
//   - PV  B-frag = 2x ds_read_b64_tr_b16 (kv-contiguous per lane via HW transpose)
__global__ __launch_bounds__(256, 2) void hopfield_kernel(
    const unsigned short* __restrict__ imgb,
    const unsigned short* __restrict__ txtb,
    unsigned short* __restrict__ ob) {
  const int combo = blockIdx.y;
  const unsigned short* Qp = (combo == 0 || combo == 3) ? imgb : txtb;
  const unsigned short* Kp = (combo == 0 || combo == 2) ? imgb : txtb;
  unsigned short* Op = ob + (size_t)combo * NR * DD;

  __shared__ __align__(16) char smem[PBASE + 4 * 16 * PSTR];

  const int tid = threadIdx.x;
  const int lane = tid & 63;
  const int wid = tid >> 6;
  const int g = lane >> 4;
  const int c = lane & 15;
  const int qwb = blockIdx.x * 64 + wid * 16;

  // Q fragments held in registers for the whole kernel (A-frag: row=c, k=ks*32+8g+i)
  bf16x8 qf[16];
  #pragma unroll
  for (int ks = 0; ks < 16; ++ks)
    qf[ks] = as_bf16x8(*(const uint4*)(Qp + (size_t)(qwb + c) * DD + ks * 32 + g * 8));

  f32x4 acc[32];
  const f32x4 zero4 = {0.f, 0.f, 0.f, 0.f};
  #pragma unroll
  for (int i = 0; i < 32; ++i) acc[i] = zero4;
  float mr[4] = {-1e30f, -1e30f, -1e30f, -1e30f};

  const unsigned smA = (unsigned)(uintptr_t)smem;
  // QK^T B-frag lane-constant base: kv_local=c  (nt adds 4*4096, ks adds 256)
  const unsigned qkB = (unsigned)((c >> 2) * 4096 + (c & 3) * 32 + (g >> 1) * 128 + (g & 1) * 16);
  // tr-read base: subtile s=2g, per-lane column c
  const unsigned trb = smA + (unsigned)(2 * g) * 4096u + (unsigned)c * 8u;
  char* Pb = smem + PBASE + wid * (16 * PSTR);

  for (int kt = 0; kt < NT_K; ++kt) {
    __syncthreads();
    const int kvb = kt * KB;
    // stage K tile into subtile layout: chunk i -> LDS byte 16*i;
    // i = s*256 + t*8 + r*2 + h ; global elem = (kvb+4s+r)*DD + t*16 + h*8
    #pragma unroll
    for (int jj = 0; jj < 4; ++jj) {
      uint4 v[4];
      #pragma unroll
      for (int q = 0; q < 4; ++q) {
        int i = (jj * 4 + q) * 256 + tid;
        int ss = i >> 8, tt = (i >> 3) & 31, rr = (i >> 1) & 3, hh = i & 1;
        v[q] = *(const uint4*)(Kp + (size_t)(kvb + 4 * ss + rr) * DD + tt * 16 + hh * 8);
      }
      #pragma unroll
      for (int q = 0; q < 4; ++q) {
        int i = (jj * 4 + q) * 256 + tid;
        *(uint4*)(smem + i * 16) = v[q];
      }
    }
    __syncthreads();

    // ---- S = Q K^T (16 q-rows x 64 kv) ----
    f32x4 sS[4];
    #pragma unroll
    for (int nt = 0; nt < 4; ++nt) sS[nt] = zero4;
    #pragma unroll
    for (int ks = 0; ks < 16; ++ks) {
      #pragma unroll
      for (int nt = 0; nt < 4; ++nt) {
        uint4 bw = *(const uint4*)(smem + qkB + (unsigned)nt * 16384u + (unsigned)ks * 256u);
        sS[nt] = __builtin_amdgcn_mfma_f32_16x16x32_bf16(qf[ks], as_bf16x8(bw), sS[nt], 0, 0, 0);
      }
    }

    // ---- online softmax (scale 8); denominator not needed (normalization cancels it) ----
    float fac[4];
    #pragma unroll
    for (int r = 0; r < 4; ++r) {
      float a0 = sS[0][r] * SCALE_H, a1 = sS[1][r] * SCALE_H;
      float a2 = sS[2][r] * SCALE_H, a3 = sS[3][r] * SCALE_H;
      float cm = fmaxf(fmaxf(a0, a1), fmaxf(a2, a3));
      cm = fmaxf(cm, __shfl_xor(cm, 1));
      cm = fmaxf(cm, __shfl_xor(cm, 2));
      cm = fmaxf(cm, __shfl_xor(cm, 4));
      cm = fmaxf(cm, __shfl_xor(cm, 8));
      float mn = fmaxf(mr[r], cm);
      fac[r] = __expf(mr[r] - mn);
      mr[r] = mn;
      float p0 = __expf(a0 - mn), p1 = __expf(a1 - mn);
      float p2 = __expf(a2 - mn), p3 = __expf(a3 - mn);
      // P[q=4g+r][kv] -> per-wave LDS scratch (row-major, stride PSTR)
      *(unsigned short*)(Pb + (4 * g + r) * PSTR + c * 2)      = f2bf(p0);
      *(unsigned short*)(Pb + (4 * g + r) * PSTR + 32 + c * 2) = f2bf(p1);
      *(unsigned short*)(Pb + (4 * g + r) * PSTR + 64 + c * 2) = f2bf(p2);
      *(unsigned short*)(Pb + (4 * g + r) * PSTR + 96 + c * 2) = f2bf(p3);
    }
    // rescale accumulator
    #pragma unroll
    for (int nt = 0; nt < 32; ++nt) {
      acc[nt][0] *= fac[0]; acc[nt][1] *= fac[1];
      acc[nt][2] *= fac[2]; acc[nt][3] *= fac[3];
    }
    // P A-fragments (row=c, kv=8g+i) and (kv=32+8g+i)
    bf16x8 pa0 = as_bf16x8(*(const uint4*)(Pb + c * PSTR + g * 16));
    bf16x8 pa1 = as_bf16x8(*(const uint4*)(Pb + c * PSTR + 64 + g * 16));

    // ---- O += P * V via hardware transpose reads ----
    #pragma unroll
    for (int np = 0; np < 16; ++np) {
      const unsigned ad0 = trb + (unsigned)(2 * np) * 128u;
      const unsigned ad1 = trb + (unsigned)(2 * np + 1) * 128u;
      u32x2 A0, B0, C0, D0, A1, B1, C1, D1;
      asm volatile("ds_read_b64_tr_b16 %0, %1" : "=v"(A0) : "v"(ad0));
      asm volatile("ds_read_b64_tr_b16 %0, %1" : "=v"(B0) : "v"(ad0 + 4096u));
      asm volatile("ds_read_b64_tr_b16 %0, %1" : "=v"(C0) : "v"(ad0 + 32768u));
      asm volatile("ds_read_b64_tr_b16 %0, %1" : "=v"(D0) : "v"(ad0 + 36864u));
      asm volatile("ds_read_b64_tr_b16 %0, %1" : "=v"(A1) : "v"(ad1));
      asm volatile("ds_read_b64_tr_b16 %0, %1" : "=v"(B1) : "v"(ad1 + 4096u));
      asm volatile("ds_read_b64_tr_b16 %0, %1" : "=v"(C1) : "v"(ad1 + 32768u));
      asm volatile("ds_read_b64_tr_b16 %0, %1" : "=v"(D1) : "v"(ad1 + 36864u));
      asm volatile("s_waitcnt lgkmcnt(0)" ::: "memory");
      __builtin_amdgcn_sched_barrier(0);
      acc[2 * np]     = __builtin_amdgcn_mfma_f32_16x16x32_bf16(pa0, pack_tr(A0, B0), acc[2 * np],     0, 0, 0);
      acc[2 * np]     = __builtin_amdgcn_mfma_f32_16x16x32_bf16(pa1, pack_tr(C0, D0), acc[2 * np],     0, 0, 0);
      acc[2 * np + 1] = __builtin_amdgcn_mfma_f32_16x16x32_bf16(pa0, pack_tr(A1, B1), acc[2 * np + 1], 0, 0, 0);
      acc[2 * np + 1] = __builtin_amdgcn_mfma_f32_16x16x32_bf16(pa1, pack_tr(C1, D1), acc[2 * np + 1], 0, 0, 0);
    }
  }

  // ---- normalize rows and store bf16 ----
  float rn[4];
  #pragma unroll
  for (int r = 0; r < 4; ++r) {
    float s = 0.f;
    #pragma unroll
    for (int nt = 0; nt < 32; ++nt) { float v = acc[nt][r]; s += v * v; }
    s += __shfl_xor(s, 1); s += __shfl_xor(s, 2);
    s += __shfl_xor(s, 4); s += __shfl_xor(s, 8);
    rn[r] = rsqrtf(s);
  }
  #pragma unroll
  for (int nt = 0; nt < 32; ++nt) {
    #pragma unroll
    for (int r = 0; r < 4; ++r)
      Op[(size_t)(qwb + 4 * g + r) * DD + nt * 16 + c] = f2bf(acc[nt][r] * rn[r]);
  }
}

// ---------------- infoloob: streaming lse + diag ----------------
// pair 0: X=slot0 (o_xx), Y=slot2 (o_xy) | pair 1: X=slot1 (o_yy), Y=slot3 (o_yx)
__global__ __launch_bounds__(256, 4) void infoloob_kernel(
    const unsigned short* __restrict__ ob, float* __restrict__ accum) {
  const int pair = blockIdx.y;
  const unsigned short* X = ob + (size_t)pair * NR * DD;
  const unsigned short* Y = ob + (size_t)(pair + 2) * NR * DD;
  __shared__ __align__(16) char smem[KB * YSTRB];

  const int tid = threadIdx.x;
  const int lane = tid & 63;
  const int wid = tid >> 6;
  const int g = lane >> 4;
  const int c = lane & 15;
  const int rowb = blockIdx.x * 64 + wid * 16;

  bf16x8 qf[16];
  #pragma unroll
  for (int ks = 0; ks < 16; ++ks)
    qf[ks] = as_bf16x8(*(const uint4*)(X + (size_t)(rowb + c) * DD + ks * 32 + g * 8));

  float mr[4] = {-1e30f, -1e30f, -1e30f, -1e30f};
  float lr[4] = {0.f, 0.f, 0.f, 0.f};
  float dacc = 0.f;
  const f32x4 zero4 = {0.f, 0.f, 0.f, 0.f};

  for (int kt = 0; kt < NT_K; ++kt) {
    __syncthreads();
    #pragma unroll
    for (int jj = 0; jj < 4; ++jj) {
      uint4 v[4];
      #pragma unroll
      for (int q = 0; q < 4; ++q) {
        int i = (jj * 4 + q) * 256 + tid;
        int row = i >> 6, cc = i & 63;
        v[q] = *(const uint4*)(Y + (size_t)(kt * KB + row) * DD + cc * 8);
      }
      #pragma unroll
      for (int q = 0; q < 4; ++q) {
        int i = (jj * 4 + q) * 256 + tid;
        int row = i >> 6, cc = i & 63;
        *(uint4*)(smem + row * YSTRB + cc * 16) = v[q];
      }
    }
    __syncthreads();

    f32x4 sS[4];
    #pragma unroll
    for (int nt = 0; nt < 4; ++nt) sS[nt] = zero4;
    #pragma unroll
    for (int ks = 0; ks < 16; ++ks) {
      #pragma unroll
      for (int nt = 0; nt < 4; ++nt) {
        uint4 bw = *(const uint4*)(smem + (nt * 16 + c) * YSTRB + ks * 64 + g * 16);
        sS[nt] = __builtin_amdgcn_mfma_f32_16x16x32_bf16(qf[ks], as_bf16x8(bw), sS[nt], 0, 0, 0);
      }
    }

    const bool hd = (kt == blockIdx.x);   // only this tile can contain the diagonal
    #pragma unroll
    for (int r = 0; r < 4; ++r) {
      float a[4];
      #pragma unroll
      for (int nt = 0; nt < 4; ++nt) a[nt] = sS[nt][r] * ITAU;
      if (hd) {
        const int ig = rowb + 4 * g + r;
        #pragma unroll
        for (int nt = 0; nt < 4; ++nt) {
          int j = kt * KB + nt * 16 + c;
          if (j == ig) { dacc += a[nt]; a[nt] = -1e30f; }
        }
      }
      float cm = fmaxf(fmaxf(a[0], a[1]), fmaxf(a[2], a[3]));
      cm = fmaxf(cm, __shfl_xor(cm, 1));
      cm = fmaxf(cm, __shfl_xor(cm, 2));
      cm = fmaxf(cm, __shfl_xor(cm, 4));
      cm = fmaxf(cm, __shfl_xor(cm, 8));
      float mn = fmaxf(mr[r], cm);
      float f = __expf(mr[r] - mn);
      float ps = __expf(a[0] - mn) + __expf(a[1] - mn) + __expf(a[2] - mn) + __expf(a[3] - mn);
      ps += __shfl_xor(ps, 1); ps += __shfl_xor(ps, 2);
      ps += __shfl_xor(ps, 4); ps += __shfl_xor(ps, 8);
      lr[r] = lr[r] * f + ps;
      mr[r] = mn;
    }
  }

  float ls = 0.f;
  #pragma unroll
  for (int r = 0; r < 4; ++r) ls += mr[r] + __logf(lr[r]);
  ls += __shfl_xor(ls, 16);
  ls += __shfl_xor(ls, 32);
  float ds = dacc;
  ds += __shfl_xor(ds, 1);  ds += __shfl_xor(ds, 2);  ds += __shfl_xor(ds, 4);
  ds += __shfl_xor(ds, 8);  ds += __shfl_xor(ds, 16); ds += __shfl_xor(ds, 32);
  if (lane == 0) {
    atomicAdd(&accum[2 * pair], ls);
    atomicAdd(&accum[2 * pair + 1], ds);
  }
}

__global__ void final_kernel(const float* a, float* o) {
  if (threadIdx.x == 0)
    o[0] = 0.5f * ((a[0] - a[1]) + (a[2] - a[3])) / (float)NR;
}

extern "C" void kernel_launch(void* const* d_in, const int* in_sizes, int n_in,
                              void* d_out, int out_size, void* d_ws, size_t ws_size,
                              hipStream_t stream) {
  (void)in_sizes; (void)n_in; (void)out_size; (void)ws_size;
  const float* img = (const float*)d_in[0];
  const float* txt = (const float*)d_in[1];
  const size_t ND = (size_t)NR * DD;
  unsigned short* imgb = (unsigned short*)d_ws;
  unsigned short* txtb = imgb + ND;
  unsigned short* ob   = txtb + ND;           // 4 x [N,D] bf16 outputs
  float* accum = (float*)(ob + 4 * ND);       // 4 f32 partial sums

  cvt_kernel<<<dim3(2 * (NR * DD / 4) / 256), dim3(256), 0, stream>>>(img, txt, imgb, txtb);
  init_kernel<<<dim3(1), dim3(64), 0, stream>>>(accum);
  hopfield_kernel<<<dim3(NR / 64, 4), dim3(256), 0, stream>>>(imgb, txtb, ob);
  infoloob_kernel<<<dim3(NR / 64, 2), dim3(256), 0, stream>>>(ob, accum);
  final_kernel<<<dim3(1), dim3(64), 0, stream>>>(accum, (float*)d_out);
}

// Round 2
// 1360.146 us; speedup vs baseline: 1.1327x; 1.1327x over previous
//
#include <hip/hip_runtime.h>
#include <stdint.h>

#define NR 8192
#define DD 512
#define KB 32
#define NT (NR / KB)            // 256 tiles
#define SCALE_H 8.0f
#define ITAU 30.0f
#define PSTR 80                 // P row stride bytes (32 kv * 2B + pad)
#define TILE_B (KB * DD * 2)    // 32768 bytes per K tile
#define THR_DEF 8.0f

typedef __bf16 bf16x8 __attribute__((ext_vector_type(8)));
typedef float f32x4 __attribute__((ext_vector_type(4)));
typedef unsigned int u32x2 __attribute__((ext_vector_type(2)));

__device__ __forceinline__ bf16x8 as_bf16x8(uint4 u) {
  union { uint4 a; bf16x8 b; } x; x.a = u; return x.b;
}
__device__ __forceinline__ unsigned short f2bf(float f) {
  unsigned u = __float_as_uint(f);
  u += 0x7FFFu + ((u >> 16) & 1u);
  return (unsigned short)(u >> 16);
}
__device__ __forceinline__ bf16x8 pack_tr(u32x2 a, u32x2 b) {
  uint4 w; w.x = a[0]; w.y = a[1]; w.z = b[0]; w.w = b[1];
  return as_bf16x8(w);
}
// async global->LDS, 16B per lane; LDS dest is wave-uniform base + lane*16,
// global src is per-lane (pre-swizzled source pattern, m173)
__device__ __forceinline__ void gload16(const void* g, void* l) {
  __builtin_amdgcn_global_load_lds((__attribute__((address_space(1))) void*)g,
                                   (__attribute__((address_space(3))) void*)l,
                                   16, 0, 0);
}

// ---------------- fp32 -> bf16 conversion ----------------
__global__ void cvt_kernel(const float* __restrict__ a, const float* __restrict__ b,
                           unsigned short* __restrict__ oa, unsigned short* __restrict__ ob) {
  const int n4 = NR * DD / 4;
  int t = blockIdx.x * blockDim.x + threadIdx.x;
  const float4* s; unsigned short* d; int i;
  if (t < n4) { s = (const float4*)a; d = oa; i = t; }
  else        { s = (const float4*)b; d = ob; i = t - n4; }
  float4 v = s[i];
  ushort4 o;
  o.x = f2bf(v.x); o.y = f2bf(v.y); o.z = f2bf(v.z); o.w = f2bf(v.w);
  *(ushort4*)(d + 4 * (size_t)i) = o;
}

__global__ void init_kernel(float* a) { if (threadIdx.x < 4) a[threadIdx.x] = 0.f; }

// ---------------- hopfield: flash attention + row normalize ----------------
// K tile LDS subtile layout [s=kv/4][t=d/16][4][16] (128B subtiles):
//   QK^T B-frag = ds_read_b128, PV B-frag = ds_read_b64_tr_b16.
// Double-buffered; staged direct with global_load_lds (per-lane global src).
__global__ __launch_bounds__(256, 2) void hopfield_kernel(
    const unsigned short* __restrict__ imgb,
    const unsigned short* __restrict__ txtb,
    unsigned short* __restrict__ ob) {
  const int combo = blockIdx.y;
  const unsigned short* Qp = (combo == 0 || combo == 3) ? imgb : txtb;
  const unsigned short* Kp = (combo == 0 || combo == 2) ? imgb : txtb;
  unsigned short* Op = ob + (size_t)combo * NR * DD;

  __shared__ __align__(16) char smem[2 * TILE_B + 4 * 16 * PSTR];

  const int tid = threadIdx.x;
  const int lane = tid & 63;
  const int wid = tid >> 6;
  const int g = lane >> 4;
  const int c = lane & 15;
  const int qwb = blockIdx.x * 64 + wid * 16;

  // Q fragments in registers for the whole kernel (A-frag: row=c, k=ks*32+8g+i)
  bf16x8 qf[16];
  #pragma unroll
  for (int ks = 0; ks < 16; ++ks)
    qf[ks] = as_bf16x8(*(const uint4*)(Qp + (size_t)(qwb + c) * DD + ks * 32 + g * 8));

  f32x4 acc[32];
  const f32x4 zero4 = {0.f, 0.f, 0.f, 0.f};
  #pragma unroll
  for (int i = 0; i < 32; ++i) acc[i] = zero4;
  float mr[4] = {-1e30f, -1e30f, -1e30f, -1e30f};

  // staging: chunk i = q*256+tid -> LDS byte 16*i; global row kvb+4q+r_, col t_*16+h_*8
  const int poff = ((tid >> 1) & 3) * DD + (tid >> 3) * 16 + (tid & 1) * 8;
  char* lbase = smem + wid * 1024;

  const unsigned qkB = (unsigned)((c >> 2) * 4096 + (c & 3) * 32 + (g >> 1) * 128 + (g & 1) * 16);
  const unsigned trb0 = (unsigned)(2 * g) * 4096u + (unsigned)c * 8u;
  char* Pb = smem + 2 * TILE_B + wid * (16 * PSTR);

  // prologue: stage tile 0 into buf 0
  {
    const unsigned short* gp = Kp + poff;
    #pragma unroll
    for (int q = 0; q < 8; ++q) gload16(gp + q * 4 * DD, lbase + q * 4096);
  }
  __syncthreads();

  for (int kt = 0; kt < NT; ++kt) {
    const int cur = kt & 1;
    // stage next tile into the other buffer; drains only at this tile's end barrier
    if (kt + 1 < NT) {
      const unsigned short* gp = Kp + (size_t)(kt + 1) * KB * DD + poff;
      char* lb = lbase + (cur ^ 1) * TILE_B;
      #pragma unroll
      for (int q = 0; q < 8; ++q) gload16(gp + q * 4 * DD, lb + q * 4096);
    }
    const char* kb = smem + cur * TILE_B;

    // ---- S = Q K^T (16 q-rows x 32 kv) ----
    f32x4 sS[2] = {zero4, zero4};
    __builtin_amdgcn_s_setprio(1);
    #pragma unroll
    for (int ks = 0; ks < 16; ++ks) {
      #pragma unroll
      for (int nt = 0; nt < 2; ++nt) {
        uint4 bw = *(const uint4*)(kb + qkB + (unsigned)nt * 16384u + (unsigned)ks * 256u);
        sS[nt] = __builtin_amdgcn_mfma_f32_16x16x32_bf16(qf[ks], as_bf16x8(bw), sS[nt], 0, 0, 0);
      }
    }
    __builtin_amdgcn_s_setprio(0);

    // ---- online softmax, defer-max (THR=8): skip acc rescale when max didn't grow ----
    float pm[4];
    bool need = false;
    #pragma unroll
    for (int r = 0; r < 4; ++r) {
      float cm = fmaxf(sS[0][r], sS[1][r]);
      cm = fmaxf(cm, __shfl_xor(cm, 1));
      cm = fmaxf(cm, __shfl_xor(cm, 2));
      cm = fmaxf(cm, __shfl_xor(cm, 4));
      cm = fmaxf(cm, __shfl_xor(cm, 8));
      pm[r] = cm * SCALE_H;
      need = need || (pm[r] > mr[r] + THR_DEF);
    }
    if (__any(need)) {
      float fac[4];
      #pragma unroll
      for (int r = 0; r < 4; ++r) {
        float mn = fmaxf(mr[r], pm[r]);
        fac[r] = __expf(mr[r] - mn);
        mr[r] = mn;
      }
      #pragma unroll
      for (int nt = 0; nt < 32; ++nt) {
        acc[nt][0] *= fac[0]; acc[nt][1] *= fac[1];
        acc[nt][2] *= fac[2]; acc[nt][3] *= fac[3];
      }
    }
    #pragma unroll
    for (int r = 0; r < 4; ++r) {
      *(unsigned short*)(Pb + (4 * g + r) * PSTR + c * 2)      = f2bf(__expf(sS[0][r] * SCALE_H - mr[r]));
      *(unsigned short*)(Pb + (4 * g + r) * PSTR + 32 + c * 2) = f2bf(__expf(sS[1][r] * SCALE_H - mr[r]));
    }
    bf16x8 pa0 = as_bf16x8(*(const uint4*)(Pb + c * PSTR + g * 16));

    // ---- O += P*V, depth-2 counted-lgkm pipeline over 16 d-column pairs ----
    asm volatile("s_waitcnt lgkmcnt(0)" ::: "memory");   // P read + writes drained: exact counting below
    __builtin_amdgcn_sched_barrier(0);
    const unsigned trb = (unsigned)(uintptr_t)kb + trb0;
    u32x2 RA[2][4];
    #pragma unroll
    for (int pb = 0; pb < 2; ++pb) {
      unsigned ad = trb + (unsigned)(2 * pb) * 128u;
      asm volatile("ds_read_b64_tr_b16 %0, %1" : "=v"(RA[pb][0]) : "v"(ad));
      asm volatile("ds_read_b64_tr_b16 %0, %1" : "=v"(RA[pb][1]) : "v"(ad + 4096u));
      asm volatile("ds_read_b64_tr_b16 %0, %1" : "=v"(RA[pb][2]) : "v"(ad + 128u));
      asm volatile("ds_read_b64_tr_b16 %0, %1" : "=v"(RA[pb][3]) : "v"(ad + 4224u));
    }
    __builtin_amdgcn_s_setprio(1);
    #pragma unroll
    for (int np = 0; np < 16; ++np) {
      if (np < 15) { asm volatile("s_waitcnt lgkmcnt(4)" ::: "memory"); }
      else         { asm volatile("s_waitcnt lgkmcnt(0)" ::: "memory"); }
      __builtin_amdgcn_sched_barrier(0);
      const int cb = np & 1;
      acc[2 * np]     = __builtin_amdgcn_mfma_f32_16x16x32_bf16(pa0, pack_tr(RA[cb][0], RA[cb][1]), acc[2 * np],     0, 0, 0);
      acc[2 * np + 1] = __builtin_amdgcn_mfma_f32_16x16x32_bf16(pa0, pack_tr(RA[cb][2], RA[cb][3]), acc[2 * np + 1], 0, 0, 0);
      if (np < 14) {
        unsigned ad = trb + (unsigned)(2 * (np + 2)) * 128u;
        asm volatile("ds_read_b64_tr_b16 %0, %1" : "=v"(RA[cb][0]) : "v"(ad));
        asm volatile("ds_read_b64_tr_b16 %0, %1" : "=v"(RA[cb][1]) : "v"(ad + 4096u));
        asm volatile("ds_read_b64_tr_b16 %0, %1" : "=v"(RA[cb][2]) : "v"(ad + 128u));
        asm volatile("ds_read_b64_tr_b16 %0, %1" : "=v"(RA[cb][3]) : "v"(ad + 4224u));
      }
    }
    __builtin_amdgcn_s_setprio(0);
    __syncthreads();   // drains vmcnt(0): next tile's staging is complete
  }

  // ---- normalize rows (softmax denom cancels) and store bf16 ----
  float rn[4];
  #pragma unroll
  for (int r = 0; r < 4; ++r) {
    float s = 0.f;
    #pragma unroll
    for (int nt = 0; nt < 32; ++nt) { float v = acc[nt][r]; s += v * v; }
    s += __shfl_xor(s, 1); s += __shfl_xor(s, 2);
    s += __shfl_xor(s, 4); s += __shfl_xor(s, 8);
    rn[r] = rsqrtf(s);
  }
  #pragma unroll
  for (int nt = 0; nt < 32; ++nt) {
    #pragma unroll
    for (int r = 0; r < 4; ++r)
      Op[(size_t)(qwb + 4 * g + r) * DD + nt * 16 + c] = f2bf(acc[nt][r] * rn[r]);
  }
}

// ---------------- infoloob: streaming lse + diag (same staged layout) ----------------
__global__ __launch_bounds__(256, 2) void infoloob_kernel(
    const unsigned short* __restrict__ ob, float* __restrict__ accum) {
  const int pair = blockIdx.y;
  const unsigned short* X = ob + (size_t)pair * NR * DD;
  const unsigned short* Y = ob + (size_t)(pair + 2) * NR * DD;
  __shared__ __align__(16) char smem[2 * TILE_B];

  const int tid = threadIdx.x;
  const int lane = tid & 63;
  const int wid = tid >> 6;
  const int g = lane >> 4;
  const int c = lane & 15;
  const int rowb = blockIdx.x * 64 + wid * 16;

  bf16x8 qf[16];
  #pragma unroll
  for (int ks = 0; ks < 16; ++ks)
    qf[ks] = as_bf16x8(*(const uint4*)(X + (size_t)(rowb + c) * DD + ks * 32 + g * 8));

  float mr[4] = {-1e30f, -1e30f, -1e30f, -1e30f};
  float lr[4] = {0.f, 0.f, 0.f, 0.f};
  float dacc = 0.f;
  const f32x4 zero4 = {0.f, 0.f, 0.f, 0.f};

  const int poff = ((tid >> 1) & 3) * DD + (tid >> 3) * 16 + (tid & 1) * 8;
  char* lbase = smem + wid * 1024;
  const unsigned qkB = (unsigned)((c >> 2) * 4096 + (c & 3) * 32 + (g >> 1) * 128 + (g & 1) * 16);

  {
    const unsigned short* gp = Y + poff;
    #pragma unroll
    for (int q = 0; q < 8; ++q) gload16(gp + q * 4 * DD, lbase + q * 4096);
  }
  __syncthreads();

  for (int kt = 0; kt < NT; ++kt) {
    const int cur = kt & 1;
    if (kt + 1 < NT) {
      const unsigned short* gp = Y + (size_t)(kt + 1) * KB * DD + poff;
      char* lb = lbase + (cur ^ 1) * TILE_B;
      #pragma unroll
      for (int q = 0; q < 8; ++q) gload16(gp + q * 4 * DD, lb + q * 4096);
    }
    const char* kb = smem + cur * TILE_B;

    f32x4 sS[2] = {zero4, zero4};
    __builtin_amdgcn_s_setprio(1);
    #pragma unroll
    for (int ks = 0; ks < 16; ++ks) {
      #pragma unroll
      for (int nt = 0; nt < 2; ++nt) {
        uint4 bw = *(const uint4*)(kb + qkB + (unsigned)nt * 16384u + (unsigned)ks * 256u);
        sS[nt] = __builtin_amdgcn_mfma_f32_16x16x32_bf16(qf[ks], as_bf16x8(bw), sS[nt], 0, 0, 0);
      }
    }
    __builtin_amdgcn_s_setprio(0);

    const bool hd = (kt == (rowb >> 5));   // this wave's 16 rows live in one 32-col tile
    #pragma unroll
    for (int r = 0; r < 4; ++r) {
      float a0 = sS[0][r] * ITAU, a1 = sS[1][r] * ITAU;
      if (hd) {
        const int ig = rowb + 4 * g + r;
        if (kt * KB + c == ig)      { dacc += a0; a0 = -1e30f; }
        if (kt * KB + 16 + c == ig) { dacc += a1; a1 = -1e30f; }
      }
      float cm = fmaxf(a0, a1);
      cm = fmaxf(cm, __shfl_xor(cm, 1));
      cm = fmaxf(cm, __shfl_xor(cm, 2));
      cm = fmaxf(cm, __shfl_xor(cm, 4));
      cm = fmaxf(cm, __shfl_xor(cm, 8));
      float mn = fmaxf(mr[r], cm);
      float f = __expf(mr[r] - mn);
      float ps = __expf(a0 - mn) + __expf(a1 - mn);
      ps += __shfl_xor(ps, 1); ps += __shfl_xor(ps, 2);
      ps += __shfl_xor(ps, 4); ps += __shfl_xor(ps, 8);
      lr[r] = lr[r] * f + ps;
      mr[r] = mn;
    }
    __syncthreads();
  }

  float ls = 0.f;
  #pragma unroll
  for (int r = 0; r < 4; ++r) ls += mr[r] + __logf(lr[r]);
  ls += __shfl_xor(ls, 16);
  ls += __shfl_xor(ls, 32);
  float ds = dacc;
  ds += __shfl_xor(ds, 1);  ds += __shfl_xor(ds, 2);  ds += __shfl_xor(ds, 4);
  ds += __shfl_xor(ds, 8);  ds += __shfl_xor(ds, 16); ds += __shfl_xor(ds, 32);
  if (lane == 0) {
    atomicAdd(&accum[2 * pair], ls);
    atomicAdd(&accum[2 * pair + 1], ds);
  }
}

__global__ void final_kernel(const float* a, float* o) {
  if (threadIdx.x == 0)
    o[0] = 0.5f * ((a[0] - a[1]) + (a[2] - a[3])) / (float)NR;
}

extern "C" void kernel_launch(void* const* d_in, const int* in_sizes, int n_in,
                              void* d_out, int out_size, void* d_ws, size_t ws_size,
                              hipStream_t stream) {
  (void)in_sizes; (void)n_in; (void)out_size; (void)ws_size;
  const float* img = (const float*)d_in[0];
  const float* txt = (const float*)d_in[1];
  const size_t ND = (size_t)NR * DD;
  unsigned short* imgb = (unsigned short*)d_ws;
  unsigned short* txtb = imgb + ND;
  unsigned short* ob   = txtb + ND;           // 4 x [N,D] bf16 outputs
  float* accum = (float*)(ob + 4 * ND);       // 4 f32 partial sums

  cvt_kernel<<<dim3(2 * (NR * DD / 4) / 256), dim3(256), 0, stream>>>(img, txt, imgb, txtb);
  init_kernel<<<dim3(1), dim3(64), 0, stream>>>(accum);
  hopfield_kernel<<<dim3(NR / 64, 4), dim3(256), 0, stream>>>(imgb, txtb, ob);
  infoloob_kernel<<<dim3(NR / 64, 2), dim3(256), 0, stream>>>(ob, accum);
  final_kernel<<<dim3(1), dim3(64), 0, stream>>>(accum, (float*)d_out);
}